// Round 2
// baseline (571.099 us; speedup 1.0000x reference)
//
#include <hip/hip_runtime.h>

typedef __bf16 bf16x8 __attribute__((ext_vector_type(8)));
typedef __bf16 bf16x4 __attribute__((ext_vector_type(4)));
typedef float f32x4 __attribute__((ext_vector_type(4)));

// ---------------------------------------------------------------------------
// Fused prep (weight transpose+cast) + LayerNorm, one dispatch.
// Blocks [0, ntiles): 32x32 LDS-tiled transpose of W_down / W_up -> bf16 [N][K]
// Blocks [ntiles, ntiles + M/4): LayerNorm, ONE WAVE PER ROW, ONE PASS:
//   row cached in registers (static-indexed unrolled array, D<=4096),
//   sum/sumsq via shfl_xor butterfly, normalize from regs, write bf16x8.
// ---------------------------------------------------------------------------
__global__ __launch_bounds__(256) void prep_ln_kernel(
    const float* __restrict__ Wd, __bf16* __restrict__ Wtd,
    const float* __restrict__ Wu, __bf16* __restrict__ Wtu,
    const float* __restrict__ x, const float* __restrict__ g,
    const float* __restrict__ be, __bf16* __restrict__ y,
    int D, int Db, int ntiles) {
    if ((int)blockIdx.x < ntiles) {
        // ---- weight transpose ----
        const float* W;
        __bf16* Wt;
        int K, N, tile;
        const int ntile_d = (Db / 32) * (D / 32);
        if ((int)blockIdx.x < ntile_d) {
            W = Wd; Wt = Wtd; K = D; N = Db; tile = blockIdx.x;
        } else {
            W = Wu; Wt = Wtu; K = Db; N = D; tile = blockIdx.x - ntile_d;
        }
        const int tn = tile % (N / 32), tk = tile / (N / 32);
        const int n0 = tn * 32, k0 = tk * 32;
        __shared__ float t[32][33];
        const int c = threadIdx.x & 31, r0 = threadIdx.x >> 5;
#pragma unroll
        for (int r = r0; r < 32; r += 8)
            t[r][c] = W[(size_t)(k0 + r) * N + n0 + c];
        __syncthreads();
#pragma unroll
        for (int r = r0; r < 32; r += 8)
            Wt[(size_t)(n0 + r) * K + k0 + c] = (__bf16)t[c][r];
        return;
    }
    // ---- LayerNorm: wave-per-row, one global read ----
    const int t = threadIdx.x;
    const int wv = t >> 6, ln = t & 63;
    const size_t row = (size_t)(blockIdx.x - ntiles) * 4 + wv;
    const float4* xr = (const float4*)(x + row * (size_t)D);
    const int nv = D >> 3;  // float8 chunks per row (D=2048 -> 256)
    float4 xs[16];          // static-indexed (full unroll) -> stays in VGPRs
    float s = 0.f, ss = 0.f;
#pragma unroll
    for (int ii = 0; ii < 8; ++ii) {
        const int i = ii * 64 + ln;
        if (i < nv) {
            float4 v0 = xr[i * 2], v1 = xr[i * 2 + 1];
            xs[2 * ii] = v0;
            xs[2 * ii + 1] = v1;
            s += v0.x + v0.y + v0.z + v0.w + v1.x + v1.y + v1.z + v1.w;
            ss += v0.x * v0.x + v0.y * v0.y + v0.z * v0.z + v0.w * v0.w +
                  v1.x * v1.x + v1.y * v1.y + v1.z * v1.z + v1.w * v1.w;
        }
    }
#pragma unroll
    for (int o = 32; o > 0; o >>= 1) {
        s += __shfl_xor(s, o);
        ss += __shfl_xor(ss, o);
    }
    const float mu = s / (float)D;
    const float rstd = rsqrtf(ss / (float)D - mu * mu + 1e-5f);
    const float4* gg = (const float4*)g;
    const float4* bb = (const float4*)be;
    bf16x8* yr = (bf16x8*)(y + row * (size_t)D);
#pragma unroll
    for (int ii = 0; ii < 8; ++ii) {
        const int i = ii * 64 + ln;
        if (i < nv) {
            float4 v0 = xs[2 * ii], v1 = xs[2 * ii + 1];
            float4 g0 = gg[i * 2], g1 = gg[i * 2 + 1];
            float4 b0 = bb[i * 2], b1 = bb[i * 2 + 1];
            bf16x8 o;
            o[0] = (__bf16)((v0.x - mu) * rstd * g0.x + b0.x);
            o[1] = (__bf16)((v0.y - mu) * rstd * g0.y + b0.y);
            o[2] = (__bf16)((v0.z - mu) * rstd * g0.z + b0.z);
            o[3] = (__bf16)((v0.w - mu) * rstd * g0.w + b0.w);
            o[4] = (__bf16)((v1.x - mu) * rstd * g1.x + b1.x);
            o[5] = (__bf16)((v1.y - mu) * rstd * g1.y + b1.y);
            o[6] = (__bf16)((v1.z - mu) * rstd * g1.z + b1.z);
            o[7] = (__bf16)((v1.w - mu) * rstd * g1.w + b1.w);
            yr[i] = o;
        }
    }
}

// ---------------------------------------------------------------------------
// ZERO-LDS direct-global MFMA GEMM.
// Both operands are cache-resident (weights 2MB -> L2; activations L3),
// so each MFMA fragment is loaded straight from global as one 16B bf16x8:
//   A-frag lane(c,q):  A [(row0 + i*16 + c)*K + k0 + q*8 .. +7]
//   W-frag lane(c,q):  Bt[(col0 + j*16 + c)*K + k0 + q*8 .. +7]
// (byte-identical register contents to the previous LDS path).
// Each WAVE owns an independent WMxWN output tile: no barriers, no LDS,
// no DMA serialization. Latency hidden by unroll-4 independent loads
// (~24-32 in flight/wave) x VGPR-bound occupancy (~12-16 waves/CU).
// Block's 4 consecutive waves share the same A rows (tn varies fastest)
// -> A-frags are L1-hot after the first wave touches them.
// EPI 0: out = silu(acc + bias) -> bf16.  EPI 1: residual -> fp32.
// ---------------------------------------------------------------------------
template <int EPI, int WM, int WN>
__global__ __launch_bounds__(256, 3) void gemm_direct(
    const __bf16* __restrict__ A, const __bf16* __restrict__ Bt,
    const float* __restrict__ bias, const float* __restrict__ hid,
    const float* __restrict__ alpha_p, void* __restrict__ Cout,
    int M, int N, int K) {
    constexpr int MI = WM / 16, NJ = WN / 16;
    const int wave = threadIdx.x >> 6;
    const int lane = threadIdx.x & 63;
    const int wid = blockIdx.x * 4 + wave;
    const int ntn = N / WN;
    const int tm = wid / ntn, tn = wid % ntn;  // tn fastest: block shares A rows
    const int row0 = tm * WM, col0 = tn * WN;
    const int c = lane & 15;  // operand non-k index
    const int q = lane >> 4;  // k-chunk quad

    f32x4 acc[MI][NJ] = {};

    const __bf16* pA[MI];
    const __bf16* pB[NJ];
#pragma unroll
    for (int i = 0; i < MI; ++i)
        pA[i] = A + (size_t)(row0 + i * 16 + c) * K + q * 8;
#pragma unroll
    for (int j = 0; j < NJ; ++j)
        pB[j] = Bt + (size_t)(col0 + j * 16 + c) * K + q * 8;

    const int nk = K / 32;
#pragma unroll 4
    for (int it = 0; it < nk; ++it) {
        const int ko = it * 32;
        bf16x8 af[NJ], bf_[MI];
#pragma unroll
        for (int j = 0; j < NJ; ++j)
            af[j] = *(const bf16x8*)(pB[j] + ko);
#pragma unroll
        for (int i = 0; i < MI; ++i)
            bf_[i] = *(const bf16x8*)(pA[i] + ko);
#pragma unroll
        for (int i = 0; i < MI; ++i)
#pragma unroll
            for (int j = 0; j < NJ; ++j)
                acc[i][j] = __builtin_amdgcn_mfma_f32_16x16x32_bf16(af[j], bf_[i],
                                                                    acc[i][j], 0, 0, 0);
    }

    // Epilogue (swapped-D layout): lane holds out[rowg][colb + 0..3]
    float alpha = (EPI == 1) ? *alpha_p : 0.f;
#pragma unroll
    for (int i = 0; i < MI; ++i) {
        const int rowg = row0 + i * 16 + c;
#pragma unroll
        for (int j = 0; j < NJ; ++j) {
            const int colb = col0 + j * 16 + q * 4;
            const float4 bv = *(const float4*)(bias + colb);
            float v0 = acc[i][j][0] + bv.x;
            float v1 = acc[i][j][1] + bv.y;
            float v2 = acc[i][j][2] + bv.z;
            float v3 = acc[i][j][3] + bv.w;
            const size_t idx = (size_t)rowg * N + colb;
            if (EPI == 0) {
                bf16x4 o;
                o[0] = (__bf16)(v0 / (1.f + __expf(-v0)));
                o[1] = (__bf16)(v1 / (1.f + __expf(-v1)));
                o[2] = (__bf16)(v2 / (1.f + __expf(-v2)));
                o[3] = (__bf16)(v3 / (1.f + __expf(-v3)));
                *(bf16x4*)((__bf16*)Cout + idx) = o;
            } else {
                const float4 h = *(const float4*)(hid + idx);
                float4 o;
                o.x = h.x + alpha * (v0 - h.x);
                o.y = h.y + alpha * (v1 - h.y);
                o.z = h.z + alpha * (v2 - h.z);
                o.w = h.w + alpha * (v3 - h.w);
                *(float4*)((float*)Cout + idx) = o;
            }
        }
    }
}

// ---------------------------------------------------------------------------
// Launch
// ---------------------------------------------------------------------------
extern "C" void kernel_launch(void* const* d_in, const int* in_sizes, int n_in,
                              void* d_out, int out_size, void* d_ws, size_t ws_size,
                              hipStream_t stream) {
    const float* hidden = (const float*)d_in[0];
    const float* ln_gamma = (const float*)d_in[1];
    const float* ln_beta = (const float*)d_in[2];
    const float* W_down = (const float*)d_in[3];
    const float* b_down = (const float*)d_in[4];
    const float* W_up = (const float*)d_in[5];
    const float* b_up = (const float*)d_in[6];
    const float* alpha = (const float*)d_in[7];
    float* out = (float*)d_out;

    const int D = in_sizes[2];      // 2048
    const int Db = in_sizes[4];     // 512
    const int M = in_sizes[0] / D;  // 16384

    char* w = (char*)d_ws;
    __bf16* hn = (__bf16*)w;  w += (size_t)M * D * sizeof(__bf16);
    __bf16* z = (__bf16*)w;   w += (size_t)M * Db * sizeof(__bf16);
    __bf16* Wtd = (__bf16*)w; w += (size_t)D * Db * sizeof(__bf16);  // [Db][D]
    __bf16* Wtu = (__bf16*)w; w += (size_t)Db * D * sizeof(__bf16);  // [D][Db]

    const int ntiles = 2 * (D / 32) * (Db / 32);
    prep_ln_kernel<<<ntiles + M / 4, 256, 0, stream>>>(W_down, Wtd, W_up, Wtu,
                                                       hidden, ln_gamma, ln_beta, hn,
                                                       D, Db, ntiles);

    // down-proj: 64x32 wave-tiles -> (M/64)*(Db/32)/4 = 1024 blocks, 16 waves/CU.
    gemm_direct<0, 64, 32><<<(M / 64) * (Db / 32) / 4, 256, 0, stream>>>(
        hn, Wtd, b_down, nullptr, nullptr, (void*)z, M, Db, D);

    // up-proj: 64x64 wave-tiles -> (M/64)*(D/64)/4 = 2048 blocks, VGPR-bound occ.
    gemm_direct<1, 64, 64><<<(M / 64) * (D / 64) / 4, 256, 0, stream>>>(
        z, Wtu, b_up, hidden, alpha, (void*)out, M, D, Db);
}

// Round 3
// 392.568 us; speedup vs baseline: 1.4548x; 1.4548x over previous
//
#include <hip/hip_runtime.h>

typedef __bf16 bf16x8 __attribute__((ext_vector_type(8)));
typedef __bf16 bf16x4 __attribute__((ext_vector_type(4)));
typedef float f32x4 __attribute__((ext_vector_type(4)));

#define S_BARRIER() asm volatile("s_barrier" ::: "memory")
#define WAITCNT_VM(n) asm volatile("s_waitcnt vmcnt(" #n ")" ::: "memory")
#define WAITCNT_LGKM0() asm volatile("s_waitcnt lgkmcnt(0)" ::: "memory")

// ---------------------------------------------------------------------------
// Fused prep (weight transpose+cast) + LayerNorm, one dispatch.
// Blocks [0, ntiles): 32x32 LDS-tiled transpose of W_down / W_up -> bf16 [N][K]
// Blocks [ntiles, ntiles + M/4): LayerNorm, ONE WAVE PER ROW, ONE PASS:
//   row cached in registers (static-indexed unrolled array), sum/sumsq via
//   shfl_xor butterfly, normalize from regs, write bf16x8. No block barriers.
// ---------------------------------------------------------------------------
__global__ __launch_bounds__(256) void prep_ln_kernel(
    const float* __restrict__ Wd, __bf16* __restrict__ Wtd,
    const float* __restrict__ Wu, __bf16* __restrict__ Wtu,
    const float* __restrict__ x, const float* __restrict__ g,
    const float* __restrict__ be, __bf16* __restrict__ y,
    int D, int Db, int ntiles) {
    if ((int)blockIdx.x < ntiles) {
        // ---- weight transpose ----
        const float* W;
        __bf16* Wt;
        int K, N, tile;
        const int ntile_d = (Db / 32) * (D / 32);
        if ((int)blockIdx.x < ntile_d) {
            W = Wd; Wt = Wtd; K = D; N = Db; tile = blockIdx.x;
        } else {
            W = Wu; Wt = Wtu; K = Db; N = D; tile = blockIdx.x - ntile_d;
        }
        const int tn = tile % (N / 32), tk = tile / (N / 32);
        const int n0 = tn * 32, k0 = tk * 32;
        __shared__ float t[32][33];
        const int c = threadIdx.x & 31, r0 = threadIdx.x >> 5;
#pragma unroll
        for (int r = r0; r < 32; r += 8)
            t[r][c] = W[(size_t)(k0 + r) * N + n0 + c];
        __syncthreads();
#pragma unroll
        for (int r = r0; r < 32; r += 8)
            Wt[(size_t)(n0 + r) * K + k0 + c] = (__bf16)t[c][r];
        return;
    }
    // ---- LayerNorm: wave-per-row, one global read ----
    const int t = threadIdx.x;
    const int wv = t >> 6, ln = t & 63;
    const size_t row = (size_t)(blockIdx.x - ntiles) * 4 + wv;
    const float4* xr = (const float4*)(x + row * (size_t)D);
    const int nv = D >> 3;  // float8 chunks per row (D=2048 -> 256)
    float4 xs[16];          // static-indexed (full unroll) -> stays in VGPRs
    float s = 0.f, ss = 0.f;
#pragma unroll
    for (int ii = 0; ii < 8; ++ii) {
        const int i = ii * 64 + ln;
        if (i < nv) {
            float4 v0 = xr[i * 2], v1 = xr[i * 2 + 1];
            xs[2 * ii] = v0;
            xs[2 * ii + 1] = v1;
            s += v0.x + v0.y + v0.z + v0.w + v1.x + v1.y + v1.z + v1.w;
            ss += v0.x * v0.x + v0.y * v0.y + v0.z * v0.z + v0.w * v0.w +
                  v1.x * v1.x + v1.y * v1.y + v1.z * v1.z + v1.w * v1.w;
        }
    }
#pragma unroll
    for (int o = 32; o > 0; o >>= 1) {
        s += __shfl_xor(s, o);
        ss += __shfl_xor(ss, o);
    }
    const float mu = s / (float)D;
    const float rstd = rsqrtf(ss / (float)D - mu * mu + 1e-5f);
    const float4* gg = (const float4*)g;
    const float4* bb = (const float4*)be;
    bf16x8* yr = (bf16x8*)(y + row * (size_t)D);
#pragma unroll
    for (int ii = 0; ii < 8; ++ii) {
        const int i = ii * 64 + ln;
        if (i < nv) {
            float4 v0 = xs[2 * ii], v1 = xs[2 * ii + 1];
            float4 g0 = gg[i * 2], g1 = gg[i * 2 + 1];
            float4 b0 = bb[i * 2], b1 = bb[i * 2 + 1];
            bf16x8 o;
            o[0] = (__bf16)((v0.x - mu) * rstd * g0.x + b0.x);
            o[1] = (__bf16)((v0.y - mu) * rstd * g0.y + b0.y);
            o[2] = (__bf16)((v0.z - mu) * rstd * g0.z + b0.z);
            o[3] = (__bf16)((v0.w - mu) * rstd * g0.w + b0.w);
            o[4] = (__bf16)((v1.x - mu) * rstd * g1.x + b1.x);
            o[5] = (__bf16)((v1.y - mu) * rstd * g1.y + b1.y);
            o[6] = (__bf16)((v1.z - mu) * rstd * g1.z + b1.z);
            o[7] = (__bf16)((v1.w - mu) * rstd * g1.w + b1.w);
            yr[i] = o;
        }
    }
}

// ---------------------------------------------------------------------------
// Pipelined bf16 MFMA GEMM, BMxBN tile, BK=32, double-buffered LDS
// (round-0 proven schedule: stage(next) -> vmcnt(L) -> barrier -> ds_read +
//  MFMA -> lgkmcnt(0) -> barrier). L = DMAs/wave/stage stays in flight.
// - global_load_lds width=16; XOR bank swizzle on 16B k-chunks:
//   LDS row r chunk p holds global chunk p^(r&3); reader XORs q^(c&3).
// - OPERAND-SWAP mfma(W,act,acc): lane (c,q) reg r <-> out[row=c][col=q*4+r],
//   4 consecutive output columns per lane -> float4 epilogue.
// A: activations [M][K] bf16; Bt: weights [N][K] bf16.
// EPI 0: out = silu(acc + bias) -> bf16.  EPI 1: residual -> fp32 (hid loads
// hoisted per output row for epilogue MLP).
// BM=64 variant (down-proj): 24KB LDS -> 6 blocks/CU, 1024 blocks; fixes the
// 2-blocks/CU starvation that left the 64-iter K-loop latency-exposed.
// ---------------------------------------------------------------------------
template <int EPI, int BM, int BN, int MINW>
__global__ __launch_bounds__(256, MINW) void gemm_bt(
    const __bf16* __restrict__ A, const __bf16* __restrict__ Bt,
    const float* __restrict__ bias, const float* __restrict__ hid,
    const float* __restrict__ alpha_p, void* __restrict__ Cout,
    int M, int N, int K) {
    constexpr int BK = 32;
    constexpr int WM = BM / 2, WN = BN / 2;  // 2x2 wave grid
    constexpr int MI = WM / 16, NJ = WN / 16;
    constexpr int GA = BM / 64, GB = BN / 64;  // 16-row groups staged per wave
    constexpr int L = GA + GB;                 // DMAs per wave per stage
    __shared__ __align__(16) __bf16 Ads[2][BM * BK];
    __shared__ __align__(16) __bf16 Bds[2][BN * BK];

    const int tid = threadIdx.x;
    const int wave = tid >> 6;
    const int lane = tid & 63;
    const int bn = blockIdx.x, bm = blockIdx.y;
    const int row0 = bm * BM, col0 = bn * BN;
    const int wr = wave >> 1, wc = wave & 1;

    f32x4 acc[MI][NJ] = {};

    const __bf16* Ag = A + (size_t)row0 * K;
    const __bf16* Bg = Bt + (size_t)col0 * K;
    const int lrow = lane >> 2;                    // 0..15 within 16-row group
    const int lk = ((lane & 3) ^ (lrow & 3)) * 8;  // swizzled k-chunk (elements)

    const int c = lane & 15;  // operand non-k index
    const int q = lane >> 4;  // quad

    auto stage = [&](int k0, int b) {
#pragma unroll
        for (int p = 0; p < GA; ++p) {
            const int r = wave * (16 * GA) + p * 16;  // wave-uniform A group
            __builtin_amdgcn_global_load_lds(
                (__attribute__((address_space(1))) void*)(Ag + (size_t)(r + lrow) * K + k0 + lk),
                (__attribute__((address_space(3))) void*)(&Ads[b][r * BK]),
                16, 0, 0);
        }
#pragma unroll
        for (int p = 0; p < GB; ++p) {
            const int r = wave * (16 * GB) + p * 16;  // wave-uniform B group
            __builtin_amdgcn_global_load_lds(
                (__attribute__((address_space(1))) void*)(Bg + (size_t)(r + lrow) * K + k0 + lk),
                (__attribute__((address_space(3))) void*)(&Bds[b][r * BK]),
                16, 0, 0);
        }
    };

    const int nk = K / BK;
    stage(0, 0);
    for (int it = 0; it < nk; ++it) {
        const int cur = it & 1;
        if (it + 1 < nk) {
            stage((it + 1) * BK, cur ^ 1);
            if constexpr (L == 3) WAITCNT_VM(3); else WAITCNT_VM(4);
        } else {
            WAITCNT_VM(0);
        }
        S_BARRIER();  // everyone's current-tile DMAs landed

        bf16x8 afW[NJ], bfA[MI];
#pragma unroll
        for (int j = 0; j < NJ; ++j) {
            const int rl = wc * WN + j * 16 + c;
            afW[j] = *(const bf16x8*)(&Bds[cur][rl * BK + ((q ^ (c & 3)) * 8)]);
        }
#pragma unroll
        for (int i = 0; i < MI; ++i) {
            const int rl = wr * WM + i * 16 + c;
            bfA[i] = *(const bf16x8*)(&Ads[cur][rl * BK + ((q ^ (c & 3)) * 8)]);
        }
#pragma unroll
        for (int i = 0; i < MI; ++i)
#pragma unroll
            for (int j = 0; j < NJ; ++j)
                acc[i][j] = __builtin_amdgcn_mfma_f32_16x16x32_bf16(afW[j], bfA[i],
                                                                    acc[i][j], 0, 0, 0);
        WAITCNT_LGKM0();  // my LDS reads retired
        S_BARRIER();      // buffer `cur` safe to overwrite next iteration
    }

    // Epilogue (swapped-D layout): lane holds out[rowg][colb + 0..3]
    float alpha = (EPI == 1) ? *alpha_p : 0.f;
#pragma unroll
    for (int i = 0; i < MI; ++i) {
        const int rowg = row0 + wr * WM + i * 16 + c;
        if (EPI == 0) {
#pragma unroll
            for (int j = 0; j < NJ; ++j) {
                const int colb = col0 + wc * WN + j * 16 + q * 4;
                const float4 bv = *(const float4*)(bias + colb);
                float v0 = acc[i][j][0] + bv.x;
                float v1 = acc[i][j][1] + bv.y;
                float v2 = acc[i][j][2] + bv.z;
                float v3 = acc[i][j][3] + bv.w;
                const size_t idx = (size_t)rowg * N + colb;
                bf16x4 o;
                o[0] = (__bf16)(v0 / (1.f + __expf(-v0)));
                o[1] = (__bf16)(v1 / (1.f + __expf(-v1)));
                o[2] = (__bf16)(v2 / (1.f + __expf(-v2)));
                o[3] = (__bf16)(v3 / (1.f + __expf(-v3)));
                *(bf16x4*)((__bf16*)Cout + idx) = o;
            }
        } else {
            // hoist all NJ hid loads for this output row -> NJ outstanding
            float4 hv[NJ];
#pragma unroll
            for (int j = 0; j < NJ; ++j) {
                const int colb = col0 + wc * WN + j * 16 + q * 4;
                hv[j] = *(const float4*)(hid + (size_t)rowg * N + colb);
            }
#pragma unroll
            for (int j = 0; j < NJ; ++j) {
                const int colb = col0 + wc * WN + j * 16 + q * 4;
                const float4 bv = *(const float4*)(bias + colb);
                float v0 = acc[i][j][0] + bv.x;
                float v1 = acc[i][j][1] + bv.y;
                float v2 = acc[i][j][2] + bv.z;
                float v3 = acc[i][j][3] + bv.w;
                float4 o;
                o.x = hv[j].x + alpha * (v0 - hv[j].x);
                o.y = hv[j].y + alpha * (v1 - hv[j].y);
                o.z = hv[j].z + alpha * (v2 - hv[j].z);
                o.w = hv[j].w + alpha * (v3 - hv[j].w);
                *(float4*)((float*)Cout + (size_t)rowg * N + colb) = o;
            }
        }
    }
}

// ---------------------------------------------------------------------------
// Launch
// ---------------------------------------------------------------------------
extern "C" void kernel_launch(void* const* d_in, const int* in_sizes, int n_in,
                              void* d_out, int out_size, void* d_ws, size_t ws_size,
                              hipStream_t stream) {
    const float* hidden = (const float*)d_in[0];
    const float* ln_gamma = (const float*)d_in[1];
    const float* ln_beta = (const float*)d_in[2];
    const float* W_down = (const float*)d_in[3];
    const float* b_down = (const float*)d_in[4];
    const float* W_up = (const float*)d_in[5];
    const float* b_up = (const float*)d_in[6];
    const float* alpha = (const float*)d_in[7];
    float* out = (float*)d_out;

    const int D = in_sizes[2];      // 2048
    const int Db = in_sizes[4];     // 512
    const int M = in_sizes[0] / D;  // 16384

    char* w = (char*)d_ws;
    __bf16* hn = (__bf16*)w;  w += (size_t)M * D * sizeof(__bf16);
    __bf16* z = (__bf16*)w;   w += (size_t)M * Db * sizeof(__bf16);
    __bf16* Wtd = (__bf16*)w; w += (size_t)D * Db * sizeof(__bf16);  // [Db][D]
    __bf16* Wtu = (__bf16*)w; w += (size_t)Db * D * sizeof(__bf16);  // [D][Db]

    const int ntiles = 2 * (D / 32) * (Db / 32);
    prep_ln_kernel<<<ntiles + M / 4, 256, 0, stream>>>(W_down, Wtd, W_up, Wtu,
                                                       hidden, ln_gamma, ln_beta, hn,
                                                       D, Db, ntiles);

    // down-proj: 64x128 tile -> 1024 blocks, 24KB LDS -> up to 6 blocks/CU.
    gemm_bt<0, 64, 128, 5><<<dim3(Db / 128, M / 64), 256, 0, stream>>>(
        hn, Wtd, b_down, nullptr, nullptr, (void*)z, M, Db, D);

    // up-proj: 128x128 (acc+frags = 128 unified regs caps at 4 waves/SIMD).
    gemm_bt<1, 128, 128, 4><<<dim3(D / 128, M / 128), 256, 0, stream>>>(
        z, Wtu, b_up, hidden, alpha, (void*)out, M, D, Db);
}